// Round 3
// baseline (340.318 us; speedup 1.0000x reference)
//
#include <hip/hip_runtime.h>
#include <math.h>

#define HEADS 8
#define HIDC  32
#define MODES 8
#define IN_CH 4
#define SEQ   32
#define BB    2
#define NS    64      // B*SEQ samples
#define HD    256     // HEADS*HIDC
#define NM    64      // MODES*MODES
#define NPIX  4096    // 64*64
#define TWO_PI_D 6.283185307179586476925286766559

__device__ __forceinline__ float2 f2(float a, float b){ return make_float2(a,b); }

// ---------------------------------------------------------------------------
// Partial forward DFT: per field [64][64] real -> 8x8 low modes. fp64 math.
// ---------------------------------------------------------------------------
__global__ __launch_bounds__(256) void fwd_dft_kernel(const float* __restrict__ src,
                                                      float2* __restrict__ dst){
  int f = blockIdx.x;
  const float* fld = src + (size_t)f * NPIX;
  __shared__ float   s_fld[64*65];     // padded rows
  __shared__ double2 s_cs[64];
  __shared__ double2 s_a1[64][8];
  int tid = threadIdx.x;
  for (int k = tid; k < NPIX; k += 256) s_fld[(k>>6)*65 + (k&63)] = fld[k];
  if (tid < 64){ double sv, cv; sincos(TWO_PI_D * tid / 64.0, &sv, &cv); s_cs[tid] = make_double2(cv, sv); }
  __syncthreads();
  // stage 1: A1[y][kx] = sum_x fld[y][x] * e^{-i 2pi kx x/64}
  for (int o = tid; o < 512; o += 256){
    int y = o >> 3, kx = o & 7;
    const float* row = s_fld + y*65;
    double sr = 0.0, si = 0.0;
    for (int x = 0; x < 64; ++x){
      double2 cs = s_cs[(kx*x) & 63];
      double v = (double)row[x];
      sr += v * cs.x; si -= v * cs.y;
    }
    s_a1[y][kx] = make_double2(sr, si);
  }
  __syncthreads();
  if (tid < 64){
    int ky = tid >> 3, kx = tid & 7;
    double sr = 0.0, si = 0.0;
    for (int y = 0; y < 64; ++y){
      double2 a = s_a1[y][kx];
      double2 cs = s_cs[(ky*y) & 63];
      sr += a.x*cs.x + a.y*cs.y;          // (R+iI)(c-is)
      si += a.y*cs.x - a.x*cs.y;
    }
    dst[(size_t)f*NM + tid] = f2((float)sr, (float)si);
  }
}

// ---------------------------------------------------------------------------
// Weight Grams over hidden dim d (fp64 accum).
// ---------------------------------------------------------------------------
__global__ __launch_bounds__(256) void gram_kernel(const float* __restrict__ qwr, const float* __restrict__ qwi,
                                                   const float* __restrict__ kwr, const float* __restrict__ kwi,
                                                   float2* __restrict__ G, float* __restrict__ Gdc){
  int t = blockIdx.x*256 + threadIdx.x;   // 65536 entries
  int j = t & 3, i = (t>>2)&3, T = (t>>4)&7, P = (t>>7)&7, m = t>>10;
  const float* qr = qwr + ((size_t)i*HD + P*32)*NM + m;
  const float* qi = qwi + ((size_t)i*HD + P*32)*NM + m;
  const float* kr = kwr + ((size_t)j*HD + T*32)*NM + m;
  const float* ki = kwi + ((size_t)j*HD + T*32)*NM + m;
  double grr=0.0, gri=0.0, gir=0.0, gii=0.0;
  for (int d = 0; d < 32; ++d){
    double ar = qr[(size_t)d*NM], ai = qi[(size_t)d*NM];
    double br = kr[(size_t)d*NM], bi = ki[(size_t)d*NM];
    grr += ar*br; gri += ar*bi; gir += ai*br; gii += ai*bi;
  }
  G[t] = f2((float)(grr + gii), (float)(gir - gri));  // sum qw*conj(kw)
  if (m == 0){
    int base = (P*8+T)*16 + i*4 + j;
    Gdc[base] = (float)grr; Gdc[1024+base] = (float)gri;
    Gdc[2048+base] = (float)gir; Gdc[3072+base] = (float)gii;
  }
}

// ---------------------------------------------------------------------------
// l2 logits via Parseval + softmax -> A (fp64 accum + fp64 softmax).
// ---------------------------------------------------------------------------
__global__ __launch_bounds__(256) void attn_kernel(const float2* __restrict__ Vf,
                                                   const float2* __restrict__ G,
                                                   const float* __restrict__ Gdc,
                                                   float* __restrict__ A){
  int bx = blockIdx.x;                 // 512 = (b<<8)|(hh<<5)|s
  int s = bx & 31;
  int base = ((bx >> 8) * 32) + (((bx >> 5) & 7) * 4);
  int tid = threadIdx.x;
  int t = tid & 31, mc = tid >> 5;
  __shared__ float2 s_vf[4][IN_CH][64];
  __shared__ double s_part[8][32];
  for (int k = tid; k < 4*IN_CH*64; k += 256){
    int m = k & 63, c = (k>>6)&3, smp = k>>8;
    s_vf[smp][c][m] = Vf[((size_t)(base+smp)*IN_CH + c)*NM + m];
  }
  __syncthreads();
  int sg = s >> 3, P = s & 7;
  int tg = t >> 3, T = t & 7;
  double acc = 0.0;
  for (int mm = 0; mm < 8; ++mm){
    int m = mc*8 + mm;
    int kx = m & 7, ky = m >> 3;
    double w = (kx >= 1) ? 2.0 : ((ky >= 1) ? 0.5 : 0.0);
    if (w != 0.0){
      const float2* g = G + ((size_t)m*64 + P*8 + T)*16;
      double sub = 0.0;
      for (int i = 0; i < 4; ++i){
        float2 a = s_vf[sg][i][m];
        for (int j = 0; j < 4; ++j){
          float2 b = s_vf[tg][j][m];
          double zr = (double)a.x*b.x + (double)a.y*b.y;    // Vq * conj(Vk)
          double zi = (double)a.y*b.x - (double)a.x*b.y;
          float2 gv = g[i*4+j];
          sub += zr*gv.x - zi*gv.y;        // Re(z * g)
        }
      }
      acc += w * sub;
    }
  }
  if (mc == 0){                            // DC: Re(Q)Re(K)
    const float* gdc = Gdc + (P*8+T)*16;
    double sub = 0.0;
    for (int i = 0; i < 4; ++i){
      float2 a = s_vf[sg][i][0];
      for (int j = 0; j < 4; ++j){
        float2 b = s_vf[tg][j][0];
        int o = i*4+j;
        sub += (double)a.x*b.x*gdc[o] - (double)a.x*b.y*gdc[1024+o]
             - (double)a.y*b.x*gdc[2048+o] + (double)a.y*b.y*gdc[3072+o];
      }
    }
    acc += sub;
  }
  s_part[mc][t] = acc;
  __syncthreads();
  if (tid < 32){
    double l2 = 0.0;
    for (int k = 0; k < 8; ++k) l2 += s_part[k][tid];
    l2 *= 0.5 / (4096.0 * 4096.0);         // scale(=0.5) * dx^2 * (1/HW)
    double mx = l2;
    for (int off = 16; off; off >>= 1) mx = fmax(mx, __shfl_xor(mx, off, 32));
    double e = exp(l2 - mx);
    double sm = e;
    for (int off = 16; off; off >>= 1) sm += __shfl_xor(sm, off, 32);
    A[(size_t)bx*32 + tid] = (float)(e / sm);
  }
}

// value spectra: Vvf[n][c][m] = sum_i Vf[n][i][m] * (vwr+i vwi)[i][c][m]
__global__ __launch_bounds__(256) void vconv_kernel(const float2* __restrict__ Vf,
                                                    const float* __restrict__ vwr, const float* __restrict__ vwi,
                                                    float2* __restrict__ Vvf){
  int t = blockIdx.x*256 + threadIdx.x;   // 64*256*64
  int m = t & 63, c = (t>>6) & 255, n = t >> 14;
  double sr = 0.0, si = 0.0;
  for (int i = 0; i < 4; ++i){
    float2 v = Vf[((size_t)n*IN_CH + i)*NM + m];
    double wr = vwr[((size_t)i*HD + c)*NM + m];
    double wi = vwi[((size_t)i*HD + c)*NM + m];
    sr += v.x*wr - v.y*wi;
    si += v.x*wi + v.y*wr;
  }
  Vvf[t] = f2((float)sr, (float)si);
}

// attention-weighted spectra: Uf[b*32+s][hh*32+d][m] = sum_t A * Vvf[scrambled]
__global__ __launch_bounds__(256) void uspec_kernel(const float* __restrict__ A,
                                                    const float2* __restrict__ Vvf,
                                                    float2* __restrict__ Uf){
  int t = blockIdx.x*256 + threadIdx.x;   // (n2, o2, m)
  int m = t & 63, o2 = (t>>6) & 255, n2 = t >> 14;
  int b = n2 >> 5, s = n2 & 31, hh = o2 >> 5, d = o2 & 31;
  const float* arow = A + ((size_t)((b*8+hh)*32 + s))*32;
  int nbase = b*32 + hh*4;
  double sr = 0.0, si = 0.0;
  for (int tt = 0; tt < 32; ++tt){
    double a = arow[tt];
    float2 v = Vvf[(((size_t)(nbase + (tt>>3))*HD) + ((tt&7)*32 + d))*NM + m];
    sr += a*v.x; si += a*v.y;
  }
  Uf[t] = f2((float)sr, (float)si);
}

// channel mixes: U1f = P(Uf) x u1w (complex, per-mode); S1f = Uf x s1w (real 1x1)
// P() is the rfft2(irfft2(.)) Hermitian projection the reference incurs by
// materializing u in pixel space: DC -> Re only; (ky>=1,kx=0) -> *0.5.
__global__ __launch_bounds__(256) void mix1_kernel(const float2* __restrict__ Uf,
                                                   const float* __restrict__ u1wr, const float* __restrict__ u1wi,
                                                   const float* __restrict__ s1w,
                                                   float2* __restrict__ U1f, float2* __restrict__ S1f){
  int t = blockIdx.x*256 + threadIdx.x;   // (n, o1, m): 64*32*64
  int m = t & 63, o1 = (t>>6) & 31, n = t >> 11;
  double pr = ((m & 7) == 0 && m != 0) ? 0.5 : 1.0;   // kx=0, ky>=1
  double pi = (m == 0) ? 0.0 : pr;                    // DC: drop Im
  double ur = 0.0, ui = 0.0, sr = 0.0, si = 0.0;
  for (int c = 0; c < 256; ++c){
    float2 u = Uf[((size_t)n*HD + c)*NM + m];
    double wr = u1wr[((size_t)c*HIDC + o1)*NM + m];
    double wi = u1wi[((size_t)c*HIDC + o1)*NM + m];
    double sw = s1w[o1*HD + c];
    double ux = u.x * pr, uy = u.y * pi;
    ur += ux*wr - uy*wi;
    ui += ux*wi + uy*wr;
    sr += u.x*sw; si += u.y*sw;
  }
  U1f[t] = f2((float)ur, (float)ui);
  S1f[t] = f2((float)sr, (float)si);
}

// x1 = gelu(irfft(U1f)) + irfft(S1f) + s1b   (both inverse transforms fused)
__global__ __launch_bounds__(256) void x1_kernel(const float2* __restrict__ U1f,
                                                 const float2* __restrict__ S1f,
                                                 const float* __restrict__ s1b,
                                                 float* __restrict__ x1){
  int f = blockIdx.x;            // n*32 + o1
  int o1 = f & 31;
  int tid = threadIdx.x;
  __shared__ double2 s_cs[64];
  __shared__ float2  s_gu[64], s_gs[64];
  __shared__ double2 s_tu[64][8], s_ts[64][8];
  if (tid < 64){ double sv, cv; sincos(TWO_PI_D*tid/64.0, &sv, &cv); s_cs[tid] = make_double2(cv, sv); }
  else if (tid < 128) s_gu[tid-64]  = U1f[(size_t)f*NM + tid-64];
  else if (tid < 192) s_gs[tid-128] = S1f[(size_t)f*NM + tid-128];
  __syncthreads();
  for (int o = tid; o < 512; o += 256){
    int y = o >> 3, kx = o & 7;
    double wf = (kx ? 2.0 : 1.0) * (1.0/4096.0);
    double ar=0.0, ai=0.0, br=0.0, bi=0.0;
    for (int ky = 0; ky < 8; ++ky){
      double2 cs = s_cs[(ky*y) & 63];
      float2 gu = s_gu[ky*8+kx];
      float2 gs = s_gs[ky*8+kx];
      ar += gu.x*cs.x - gu.y*cs.y;  ai += gu.x*cs.y + gu.y*cs.x;   // (R+iI)(c+is)
      br += gs.x*cs.x - gs.y*cs.y;  bi += gs.x*cs.y + gs.y*cs.x;
    }
    s_tu[y][kx] = make_double2(ar*wf, ai*wf);
    s_ts[y][kx] = make_double2(br*wf, bi*wf);
  }
  __syncthreads();
  double bias = s1b[o1];
  float* dst = x1 + (size_t)f*NPIX;
  for (int p = tid; p < NPIX; p += 256){
    int y = p >> 6, x = p & 63;
    double vu = 0.0, vs = 0.0;
    for (int kx = 0; kx < 8; ++kx){
      double2 cs = s_cs[(kx*x) & 63];
      double2 tu = s_tu[y][kx];
      double2 ts = s_ts[y][kx];
      vu += tu.x*cs.x - tu.y*cs.y;
      vs += ts.x*cs.x - ts.y*cs.y;
    }
    double g = 0.5 * vu * (1.0 + erf(vu * 0.70710678118654752440));
    dst[p] = (float)(g + vs + bias);
  }
}

// final: X2f = X1f x u2w; out = irfft(X2f) + x1 x s2w + s2b
// grid = 64 samples x 8 pixel tiles
__global__ __launch_bounds__(256) void final_kernel(const float2* __restrict__ X1f,
                                                    const float* __restrict__ u2wr, const float* __restrict__ u2wi,
                                                    const float* __restrict__ x1,
                                                    const float* __restrict__ s2w, const float* __restrict__ s2b,
                                                    float* __restrict__ out){
  int n = blockIdx.x >> 3, tile = blockIdx.x & 7;
  int tid = threadIdx.x;
  __shared__ double2 s_cs[64];
  __shared__ double2 s_x2f[4][64];
  __shared__ double2 s_tmp[4][64][8];
  __shared__ float   s_w2[128];
  __shared__ float   s_b2[4];
  if (tid < 64){ double sv, cv; sincos(TWO_PI_D*tid/64.0, &sv, &cv); s_cs[tid] = make_double2(cv, sv); }
  if (tid >= 64 && tid < 192) s_w2[tid-64] = s2w[tid-64];
  if (tid >= 192 && tid < 196) s_b2[tid-192] = s2b[tid-192];
  {
    int o2 = tid >> 6, m = tid & 63;
    double sr = 0.0, si = 0.0;
    for (int o1 = 0; o1 < 32; ++o1){
      float2 xv = X1f[((size_t)n*HIDC + o1)*NM + m];
      double wr = u2wr[((size_t)o1*IN_CH + o2)*NM + m];
      double wi = u2wi[((size_t)o1*IN_CH + o2)*NM + m];
      sr += xv.x*wr - xv.y*wi;
      si += xv.x*wi + xv.y*wr;
    }
    s_x2f[o2][m] = make_double2(sr, si);
  }
  __syncthreads();
  for (int o = tid; o < 2048; o += 256){
    int o2 = o >> 9, rem = o & 511, y = rem >> 3, kx = rem & 7;
    double wf = (kx ? 2.0 : 1.0) * (1.0/4096.0);
    double tr=0.0, ti=0.0;
    for (int ky = 0; ky < 8; ++ky){
      double2 cs = s_cs[(ky*y) & 63];
      double2 g = s_x2f[o2][ky*8+kx];
      tr += g.x*cs.x - g.y*cs.y;
      ti += g.x*cs.y + g.y*cs.x;
    }
    s_tmp[o2][y][kx] = make_double2(tr*wf, ti*wf);
  }
  __syncthreads();
  const float* xbase = x1 + (size_t)n*HIDC*NPIX;
  float* obase = out + (size_t)n*IN_CH*NPIX;
  for (int p = tile*512 + tid; p < (tile+1)*512; p += 256){
    double a0 = s_b2[0], a1 = s_b2[1], a2 = s_b2[2], a3 = s_b2[3];
    for (int c = 0; c < 32; ++c){
      double xv = xbase[(size_t)c*NPIX + p];
      a0 += (double)s_w2[c]*xv; a1 += (double)s_w2[32+c]*xv;
      a2 += (double)s_w2[64+c]*xv; a3 += (double)s_w2[96+c]*xv;
    }
    int y = p >> 6, x = p & 63;
    double sp[4];
    #pragma unroll
    for (int o2 = 0; o2 < 4; ++o2){
      double v = 0.0;
      for (int kx = 0; kx < 8; ++kx){
        double2 cs = s_cs[(kx*x) & 63];
        double2 t2 = s_tmp[o2][y][kx];
        v += t2.x*cs.x - t2.y*cs.y;
      }
      sp[o2] = v;
    }
    obase[p]          = (float)(a0 + sp[0]);
    obase[NPIX + p]   = (float)(a1 + sp[1]);
    obase[2*NPIX + p] = (float)(a2 + sp[2]);
    obase[3*NPIX + p] = (float)(a3 + sp[3]);
  }
}

extern "C" void kernel_launch(void* const* d_in, const int* in_sizes, int n_in,
                              void* d_out, int out_size, void* d_ws, size_t ws_size,
                              hipStream_t stream) {
  (void)in_sizes; (void)n_in; (void)out_size; (void)ws_size;
  const float* v    = (const float*)d_in[0];
  const float* qwr  = (const float*)d_in[1];
  const float* qwi  = (const float*)d_in[2];
  const float* kwr  = (const float*)d_in[3];
  const float* kwi  = (const float*)d_in[4];
  const float* vwr  = (const float*)d_in[5];
  const float* vwi  = (const float*)d_in[6];
  const float* u1wr = (const float*)d_in[7];
  const float* u1wi = (const float*)d_in[8];
  const float* u2wr = (const float*)d_in[9];
  const float* u2wi = (const float*)d_in[10];
  const float* s1w  = (const float*)d_in[11];
  const float* s1b  = (const float*)d_in[12];
  const float* s2w  = (const float*)d_in[13];
  const float* s2b  = (const float*)d_in[14];
  float* out = (float*)d_out;

  float* ws = (float*)d_ws;
  size_t off = 0;
  float2* Vf   = (float2*)(ws + off); off += (size_t)NS*IN_CH*NM*2;     // 32768
  float2* G    = (float2*)(ws + off); off += (size_t)65536*2;           // 131072
  float*  Gdc  =          (ws + off); off += 16384;
  float*  A    =          (ws + off); off += 16384;
  float2* Vvf  = (float2*)(ws + off); off += (size_t)NS*HD*NM*2;        // 2097152
  float2* Uf   = (float2*)(ws + off); off += (size_t)NS*HD*NM*2;        // 2097152
  float2* U1f  = (float2*)(ws + off); off += (size_t)NS*HIDC*NM*2;      // 262144
  float2* S1f  = (float2*)(ws + off); off += (size_t)NS*HIDC*NM*2;      // 262144
  float*  x1   =          (ws + off); off += (size_t)NS*HIDC*NPIX;      // 8388608
  float2* X1f  = (float2*)(ws + off); off += (size_t)NS*HIDC*NM*2;      // 262144

  fwd_dft_kernel<<<NS*IN_CH, 256, 0, stream>>>(v, Vf);
  gram_kernel<<<256, 256, 0, stream>>>(qwr, qwi, kwr, kwi, G, Gdc);
  vconv_kernel<<<4096, 256, 0, stream>>>(Vf, vwr, vwi, Vvf);
  attn_kernel<<<512, 256, 0, stream>>>(Vf, G, Gdc, A);
  uspec_kernel<<<4096, 256, 0, stream>>>(A, Vvf, Uf);
  mix1_kernel<<<512, 256, 0, stream>>>(Uf, u1wr, u1wi, s1w, U1f, S1f);
  x1_kernel<<<NS*HIDC, 256, 0, stream>>>(U1f, S1f, s1b, x1);
  fwd_dft_kernel<<<NS*HIDC, 256, 0, stream>>>(x1, X1f);
  final_kernel<<<64*8, 256, 0, stream>>>(X1f, u2wr, u2wi, x1, s2w, s2b, out);
}

// Round 4
// 224.047 us; speedup vs baseline: 1.5190x; 1.5190x over previous
//
#include <hip/hip_runtime.h>
#include <math.h>

#define HEADS 8
#define HIDC  32
#define MODES 8
#define IN_CH 4
#define SEQ   32
#define NS    64      // B*SEQ samples
#define HD    256     // HEADS*HIDC
#define NM    64      // MODES*MODES
#define NPIX  4096    // 64*64
#define TWO_PI_D 6.283185307179586476925286766559

__device__ __forceinline__ float2 f2(float a, float b){ return make_float2(a,b); }

// ---------------------------------------------------------------------------
// K1: partial forward DFT of v: per field [64][64] -> 8x8 low modes (fp32).
// ---------------------------------------------------------------------------
__global__ __launch_bounds__(256) void fwd_dft_kernel(const float* __restrict__ src,
                                                      float2* __restrict__ dst){
  int f = blockIdx.x;
  const float* fld = src + (size_t)f * NPIX;
  __shared__ float  s_fld[64*65];
  __shared__ float2 s_cs[64];
  __shared__ float2 s_a1[64][8];
  int tid = threadIdx.x;
  for (int k = tid; k < NPIX; k += 256) s_fld[(k>>6)*65 + (k&63)] = fld[k];
  if (tid < 64){ double sv, cv; sincos(TWO_PI_D * tid / 64.0, &sv, &cv); s_cs[tid] = f2((float)cv,(float)sv); }
  __syncthreads();
  for (int o = tid; o < 512; o += 256){
    int y = o >> 3, kx = o & 7;
    const float* row = s_fld + y*65;
    float sr = 0.f, si = 0.f;
    for (int x = 0; x < 64; ++x){
      float2 cs = s_cs[(kx*x) & 63];
      float v = row[x];
      sr += v * cs.x; si -= v * cs.y;
    }
    s_a1[y][kx] = f2(sr, si);
  }
  __syncthreads();
  if (tid < 64){
    int ky = tid >> 3, kx = tid & 7;
    float sr = 0.f, si = 0.f;
    for (int y = 0; y < 64; ++y){
      float2 a = s_a1[y][kx];
      float2 cs = s_cs[(ky*y) & 63];
      sr += a.x*cs.x + a.y*cs.y;
      si += a.y*cs.x - a.x*cs.y;
    }
    dst[(size_t)f*NM + tid] = f2(sr, si);
  }
}

// ---------------------------------------------------------------------------
// K2: weight Grams, block per mode m, LDS-staged; G2 pre-scaled by Parseval
// weight w_m; T-contiguous layout for attn loads. m=0 entries are 0 (DC path
// handled via Gdc).
// ---------------------------------------------------------------------------
__global__ __launch_bounds__(256) void gram_kernel(const float* __restrict__ qwr, const float* __restrict__ qwi,
                                                   const float* __restrict__ kwr, const float* __restrict__ kwi,
                                                   float2* __restrict__ G2, float* __restrict__ Gdc){
  int m = blockIdx.x, tid = threadIdx.x;
  __shared__ float qsr[4][257], qsi[4][257], ksr[4][257], ksi[4][257];
  for (int k = tid; k < 1024; k += 256){
    int i = k >> 8, c = k & 255;
    size_t a = ((size_t)(i*256 + c))*64 + m;
    qsr[i][c] = qwr[a]; qsi[i][c] = qwi[a];
    ksr[i][c] = kwr[a]; ksi[i][c] = kwi[a];
  }
  __syncthreads();
  int kx = m & 7, ky = m >> 3;
  float w = (kx >= 1) ? 2.0f : ((ky >= 1) ? 0.5f : 0.0f);
  for (int e = tid; e < 1024; e += 256){
    int P = e >> 7, T = (e >> 4) & 7, i = (e >> 2) & 3, j = e & 3;
    float grr=0.f, gri=0.f, gir=0.f, gii=0.f;
    for (int d = 0; d < 32; ++d){
      float ar = qsr[i][P*32+d], ai = qsi[i][P*32+d];
      float br = ksr[j][T*32+d], bi = ksi[j][T*32+d];
      grr += ar*br; gri += ar*bi; gir += ai*br; gii += ai*bi;
    }
    G2[(size_t)(((m*8+P)*4+i)*4+j)*8 + T] = f2(w*(grr+gii), w*(gir-gri));
    if (m == 0){
      int o = ((P*4+i)*4+j)*8 + T;
      Gdc[o] = grr; Gdc[1024+o] = gri; Gdc[2048+o] = gir; Gdc[3072+o] = gii;
    }
  }
}

// ---------------------------------------------------------------------------
// K3: attention logits via Parseval + softmax -> A (fp32).
// ---------------------------------------------------------------------------
__global__ __launch_bounds__(256) void attn_kernel(const float2* __restrict__ Vf,
                                                   const float2* __restrict__ G2,
                                                   const float* __restrict__ Gdc,
                                                   float* __restrict__ A){
  int bx = blockIdx.x;                 // (b<<8)|(hh<<5)|s
  int s = bx & 31;
  int base = ((bx >> 8) * 32) + (((bx >> 5) & 7) * 4);
  int tid = threadIdx.x;
  int t = tid & 31, mc = tid >> 5;
  __shared__ float2 s_vf[4][IN_CH][64];
  __shared__ float  s_part[8][33];
  for (int k = tid; k < 4*IN_CH*64; k += 256){
    int m = k & 63, c = (k>>6)&3, smp = k>>8;
    s_vf[smp][c][m] = Vf[((size_t)(base+smp)*IN_CH + c)*NM + m];
  }
  __syncthreads();
  int sg = s >> 3, P = s & 7;
  int tg = t >> 3, T = t & 7;
  float acc = 0.f;
  for (int mm = 0; mm < 8; ++mm){
    int m = mc*8 + mm;
    const float2* g = G2 + (size_t)((m*8+P)*16)*8 + T;
    float sub = 0.f;
    for (int i = 0; i < 4; ++i){
      float2 a = s_vf[sg][i][m];
      for (int j = 0; j < 4; ++j){
        float2 b = s_vf[tg][j][m];
        float zr = a.x*b.x + a.y*b.y;
        float zi = a.y*b.x - a.x*b.y;
        float2 gv = g[(size_t)(i*4+j)*8];
        sub += zr*gv.x - zi*gv.y;
      }
    }
    acc += sub;
  }
  if (mc == 0){                        // DC: Re(Q)Re(K) etc.
    float sub = 0.f;
    for (int i = 0; i < 4; ++i){
      float2 a = s_vf[sg][i][0];
      for (int j = 0; j < 4; ++j){
        float2 b = s_vf[tg][j][0];
        int o = ((P*4+i)*4+j)*8 + T;
        sub += a.x*b.x*Gdc[o] - a.x*b.y*Gdc[1024+o]
             - a.y*b.x*Gdc[2048+o] + a.y*b.y*Gdc[3072+o];
      }
    }
    acc += sub;
  }
  s_part[mc][t] = acc;
  __syncthreads();
  if (tid < 32){
    float l2 = 0.f;
    for (int k = 0; k < 8; ++k) l2 += s_part[k][tid];
    l2 *= 0.5f / (4096.0f * 4096.0f);  // scale * dx^2 * (1/HW)
    float mx = l2;
    for (int off = 16; off; off >>= 1) mx = fmaxf(mx, __shfl_xor(mx, off, 32));
    float e = expf(l2 - mx);
    float sm = e;
    for (int off = 16; off; off >>= 1) sm += __shfl_xor(sm, off, 32);
    A[(size_t)bx*32 + tid] = e / sm;
  }
}

// ---------------------------------------------------------------------------
// K4: fused vconv + attention-apply. Block per (b,hh,m-quad). Computes the
// value spectra slab in LDS and the A-weighted sum, writing Uf[n][m][c].
// ---------------------------------------------------------------------------
__global__ __launch_bounds__(256) void uspec_kernel(const float2* __restrict__ Vf,
                                                    const float* __restrict__ vwr, const float* __restrict__ vwi,
                                                    const float* __restrict__ A,
                                                    float2* __restrict__ Uf){
  int bid = blockIdx.x;                // b*128 + hh*16 + mq
  int b = bid >> 7, hh = (bid >> 4) & 7, mq = bid & 15, m0 = mq*4;
  int nbase = b*32 + hh*4;
  int tid = threadIdx.x;
  __shared__ float2 s_vw[4][4][256];   // [i][mm][c]
  __shared__ float2 s_vv[4][4][256];   // [smp][mm][c]
  __shared__ float  s_A[32][32];
  __shared__ float2 s_vf[4][4][4];     // [smp][i][mm]
  for (int k = tid; k < 4096; k += 256){
    int i = k >> 10, c = (k >> 2) & 255, mm = k & 3;
    size_t a = ((size_t)(i*256 + c))*64 + m0 + mm;
    s_vw[i][mm][c] = f2(vwr[a], vwi[a]);
  }
  for (int k = tid; k < 1024; k += 256)
    s_A[k>>5][k&31] = A[(size_t)((b*8+hh)*32 + (k>>5))*32 + (k&31)];
  if (tid < 64){
    int smp = tid >> 4, i = (tid >> 2) & 3, mm = tid & 3;
    s_vf[smp][i][mm] = Vf[((size_t)(nbase+smp)*4 + i)*64 + m0 + mm];
  }
  __syncthreads();
  for (int k = tid; k < 4096; k += 256){
    int smp = k >> 10, mm = (k >> 8) & 3, c = k & 255;
    float sr = 0.f, si = 0.f;
    for (int i = 0; i < 4; ++i){
      float2 v = s_vf[smp][i][mm];
      float2 w = s_vw[i][mm][c];
      sr += v.x*w.x - v.y*w.y;
      si += v.x*w.y + v.y*w.x;
    }
    s_vv[smp][mm][c] = f2(sr, si);
  }
  __syncthreads();
  int sg = tid >> 5, d = tid & 31;
  float2 acc[4][4];
  for (int ss = 0; ss < 4; ++ss)
    for (int mm = 0; mm < 4; ++mm) acc[ss][mm] = f2(0.f, 0.f);
  for (int tt = 0; tt < 32; ++tt){
    int tg = tt >> 3, c = (tt & 7)*32 + d;
    float a0 = s_A[sg*4+0][tt], a1 = s_A[sg*4+1][tt];
    float a2 = s_A[sg*4+2][tt], a3 = s_A[sg*4+3][tt];
    for (int mm = 0; mm < 4; ++mm){
      float2 v = s_vv[tg][mm][c];
      acc[0][mm].x += a0*v.x; acc[0][mm].y += a0*v.y;
      acc[1][mm].x += a1*v.x; acc[1][mm].y += a1*v.y;
      acc[2][mm].x += a2*v.x; acc[2][mm].y += a2*v.y;
      acc[3][mm].x += a3*v.x; acc[3][mm].y += a3*v.y;
    }
  }
  for (int ss = 0; ss < 4; ++ss){
    int n = b*32 + sg*4 + ss;
    for (int mm = 0; mm < 4; ++mm)
      Uf[((size_t)n*64 + m0 + mm)*256 + hh*32 + d] = acc[ss][mm];
  }
}

// ---------------------------------------------------------------------------
// K5: channel mixes. U1f = P(Uf) x u1w (Hermitian-projected), S1f = Uf x s1w.
// Block per (n, m-quarter). Uf layout [n][m][c].
// ---------------------------------------------------------------------------
__global__ __launch_bounds__(256) void mix1_kernel(const float2* __restrict__ Uf,
                                                   const float* __restrict__ u1wr, const float* __restrict__ u1wi,
                                                   const float* __restrict__ s1w,
                                                   float2* __restrict__ U1f, float2* __restrict__ S1f){
  int n = blockIdx.x >> 2, mq = blockIdx.x & 3, m0 = mq*16;
  int tid = threadIdx.x;
  __shared__ float2 s_u[16][258];
  __shared__ float  s_w1[32][257];
  for (int k = tid; k < 16*256; k += 256){
    int c = k & 255, mm = k >> 8;
    s_u[mm][c] = Uf[((size_t)n*64 + m0 + mm)*256 + c];
  }
  for (int k = tid; k < 32*256; k += 256){
    int c = k & 255, o1 = k >> 8;
    s_w1[o1][c] = s1w[o1*256 + c];
  }
  __syncthreads();
  int o1 = tid >> 3, m8 = tid & 7;
  int mA = m0 + m8, mB = m0 + m8 + 8;
  // Hermitian projection from the reference's irfft2/rfft2 round-trip:
  float prA = ((mA & 7)==0 && mA) ? 0.5f : 1.0f;  float piA = mA ? prA : 0.0f;
  float prB = ((mB & 7)==0 && mB) ? 0.5f : 1.0f;  float piB = mB ? prB : 0.0f;
  float2 au0 = f2(0,0), au1 = f2(0,0), as0 = f2(0,0), as1 = f2(0,0);
  for (int c = 0; c < 256; ++c){
    float2 uA = s_u[m8][c], uB = s_u[m8+8][c];
    float sw = s_w1[o1][c];
    size_t wb = ((size_t)c*32 + o1)*64;
    float wrA = u1wr[wb + mA], wiA = u1wi[wb + mA];
    float wrB = u1wr[wb + mB], wiB = u1wi[wb + mB];
    float xA = uA.x*prA, yA = uA.y*piA;
    float xB = uB.x*prB, yB = uB.y*piB;
    au0.x += xA*wrA - yA*wiA;  au0.y += xA*wiA + yA*wrA;
    au1.x += xB*wrB - yB*wiB;  au1.y += xB*wiB + yB*wrB;
    as0.x += uA.x*sw; as0.y += uA.y*sw;
    as1.x += uB.x*sw; as1.y += uB.y*sw;
  }
  size_t ob = (size_t)(n*32 + o1)*64;
  U1f[ob + mA] = au0; U1f[ob + mB] = au1;
  S1f[ob + mA] = as0; S1f[ob + mB] = as1;
}

// ---------------------------------------------------------------------------
// K6: x1 = gelu(irfft(U1f)) + irfft(S1f) + s1b, fused with the forward DFT of
// the produced field -> X1f (kills the 2048-block standalone DFT).
// ---------------------------------------------------------------------------
__global__ __launch_bounds__(256) void x1dft_kernel(const float2* __restrict__ U1f,
                                                    const float2* __restrict__ S1f,
                                                    const float* __restrict__ s1b,
                                                    float* __restrict__ x1,
                                                    float2* __restrict__ X1f){
  int f = blockIdx.x, o1 = f & 31, tid = threadIdx.x;
  __shared__ float2 s_cs[64];
  __shared__ float2 s_gu[64], s_gs[64];
  __shared__ float2 s_tu[64][8], s_ts[64][8];
  __shared__ float  s_fld[64*65];
  __shared__ float2 s_a1[64][8];
  if (tid < 64){ double sv, cv; sincos(TWO_PI_D*tid/64.0, &sv, &cv); s_cs[tid] = f2((float)cv,(float)sv); }
  else if (tid < 128) s_gu[tid-64]  = U1f[(size_t)f*NM + tid-64];
  else if (tid < 192) s_gs[tid-128] = S1f[(size_t)f*NM + tid-128];
  __syncthreads();
  for (int o = tid; o < 512; o += 256){
    int y = o >> 3, kx = o & 7;
    float wf = (kx ? 2.0f : 1.0f) * (1.0f/4096.0f);
    float ar=0.f, ai=0.f, br=0.f, bi=0.f;
    for (int ky = 0; ky < 8; ++ky){
      float2 cs = s_cs[(ky*y) & 63];
      float2 gu = s_gu[ky*8+kx], gs = s_gs[ky*8+kx];
      ar += gu.x*cs.x - gu.y*cs.y;  ai += gu.x*cs.y + gu.y*cs.x;
      br += gs.x*cs.x - gs.y*cs.y;  bi += gs.x*cs.y + gs.y*cs.x;
    }
    s_tu[y][kx] = f2(ar*wf, ai*wf);
    s_ts[y][kx] = f2(br*wf, bi*wf);
  }
  __syncthreads();
  float bias = s1b[o1];
  float* dst = x1 + (size_t)f*NPIX;
  for (int p = tid; p < NPIX; p += 256){
    int y = p >> 6, x = p & 63;
    float vu = 0.f, vs = 0.f;
    for (int kx = 0; kx < 8; ++kx){
      float2 cs = s_cs[(kx*x) & 63];
      float2 tu = s_tu[y][kx], ts = s_ts[y][kx];
      vu += tu.x*cs.x - tu.y*cs.y;
      vs += ts.x*cs.x - ts.y*cs.y;
    }
    float g = 0.5f * vu * (1.0f + erff(vu * 0.70710678f));
    float val = g + vs + bias;
    dst[p] = val;
    s_fld[y*65 + x] = val;
  }
  __syncthreads();
  for (int o = tid; o < 512; o += 256){
    int y = o >> 3, kx = o & 7;
    const float* row = s_fld + y*65;
    float sr = 0.f, si = 0.f;
    for (int x = 0; x < 64; ++x){
      float2 cs = s_cs[(kx*x) & 63];
      float v = row[x];
      sr += v*cs.x; si -= v*cs.y;
    }
    s_a1[y][kx] = f2(sr, si);
  }
  __syncthreads();
  if (tid < 64){
    int ky = tid >> 3, kx = tid & 7;
    float sr = 0.f, si = 0.f;
    for (int y = 0; y < 64; ++y){
      float2 a = s_a1[y][kx];
      float2 cs = s_cs[(ky*y) & 63];
      sr += a.x*cs.x + a.y*cs.y;
      si += a.y*cs.x - a.x*cs.y;
    }
    X1f[(size_t)f*NM + tid] = f2(sr, si);
  }
}

// ---------------------------------------------------------------------------
// K7: X2f = X1f x u2w; out = irfft(X2f) + x1 x s2w + s2b.
// ---------------------------------------------------------------------------
__global__ __launch_bounds__(256) void final_kernel(const float2* __restrict__ X1f,
                                                    const float* __restrict__ u2wr, const float* __restrict__ u2wi,
                                                    const float* __restrict__ x1,
                                                    const float* __restrict__ s2w, const float* __restrict__ s2b,
                                                    float* __restrict__ out){
  int n = blockIdx.x >> 3, tile = blockIdx.x & 7;
  int tid = threadIdx.x;
  __shared__ float2 s_cs[64];
  __shared__ float2 s_x2f[4][64];
  __shared__ float2 s_tmp[4][64][8];
  __shared__ float  s_w2[128];
  __shared__ float  s_b2[4];
  if (tid < 64){ double sv, cv; sincos(TWO_PI_D*tid/64.0, &sv, &cv); s_cs[tid] = f2((float)cv,(float)sv); }
  if (tid >= 64 && tid < 192) s_w2[tid-64] = s2w[tid-64];
  if (tid >= 192 && tid < 196) s_b2[tid-192] = s2b[tid-192];
  {
    int o2 = tid >> 6, m = tid & 63;
    float sr = 0.f, si = 0.f;
    for (int o1 = 0; o1 < 32; ++o1){
      float2 xv = X1f[((size_t)n*HIDC + o1)*NM + m];
      size_t wb = ((size_t)(o1*IN_CH + o2))*NM + m;
      float wr = u2wr[wb], wi = u2wi[wb];
      sr += xv.x*wr - xv.y*wi;
      si += xv.x*wi + xv.y*wr;
    }
    s_x2f[o2][m] = f2(sr, si);
  }
  __syncthreads();
  for (int o = tid; o < 2048; o += 256){
    int o2 = o >> 9, rem = o & 511, y = rem >> 3, kx = rem & 7;
    float wf = (kx ? 2.0f : 1.0f) * (1.0f/4096.0f);
    float tr=0.f, ti=0.f;
    for (int ky = 0; ky < 8; ++ky){
      float2 cs = s_cs[(ky*y) & 63];
      float2 g = s_x2f[o2][ky*8+kx];
      tr += g.x*cs.x - g.y*cs.y;
      ti += g.x*cs.y + g.y*cs.x;
    }
    s_tmp[o2][y][kx] = f2(tr*wf, ti*wf);
  }
  __syncthreads();
  const float* xbase = x1 + (size_t)n*HIDC*NPIX;
  float* obase = out + (size_t)n*IN_CH*NPIX;
  for (int p = tile*512 + tid; p < (tile+1)*512; p += 256){
    float a0 = s_b2[0], a1 = s_b2[1], a2 = s_b2[2], a3 = s_b2[3];
    for (int c = 0; c < 32; ++c){
      float xv = xbase[(size_t)c*NPIX + p];
      a0 += s_w2[c]*xv; a1 += s_w2[32+c]*xv; a2 += s_w2[64+c]*xv; a3 += s_w2[96+c]*xv;
    }
    int y = p >> 6, x = p & 63;
    float sp[4];
    #pragma unroll
    for (int o2 = 0; o2 < 4; ++o2){
      float v = 0.f;
      for (int kx = 0; kx < 8; ++kx){
        float2 cs = s_cs[(kx*x) & 63];
        float2 t2 = s_tmp[o2][y][kx];
        v += t2.x*cs.x - t2.y*cs.y;
      }
      sp[o2] = v;
    }
    obase[p]          = a0 + sp[0];
    obase[NPIX + p]   = a1 + sp[1];
    obase[2*NPIX + p] = a2 + sp[2];
    obase[3*NPIX + p] = a3 + sp[3];
  }
}

extern "C" void kernel_launch(void* const* d_in, const int* in_sizes, int n_in,
                              void* d_out, int out_size, void* d_ws, size_t ws_size,
                              hipStream_t stream) {
  (void)in_sizes; (void)n_in; (void)out_size; (void)ws_size;
  const float* v    = (const float*)d_in[0];
  const float* qwr  = (const float*)d_in[1];
  const float* qwi  = (const float*)d_in[2];
  const float* kwr  = (const float*)d_in[3];
  const float* kwi  = (const float*)d_in[4];
  const float* vwr  = (const float*)d_in[5];
  const float* vwi  = (const float*)d_in[6];
  const float* u1wr = (const float*)d_in[7];
  const float* u1wi = (const float*)d_in[8];
  const float* u2wr = (const float*)d_in[9];
  const float* u2wi = (const float*)d_in[10];
  const float* s1w  = (const float*)d_in[11];
  const float* s1b  = (const float*)d_in[12];
  const float* s2w  = (const float*)d_in[13];
  const float* s2b  = (const float*)d_in[14];
  float* out = (float*)d_out;

  float* ws = (float*)d_ws;
  size_t off = 0;
  float2* Vf   = (float2*)(ws + off); off += (size_t)NS*IN_CH*NM*2;     // 32768
  float2* G2   = (float2*)(ws + off); off += (size_t)65536*2;           // 131072
  float*  Gdc  =          (ws + off); off += 4096;
  float*  A    =          (ws + off); off += 16384;
  float2* Uf   = (float2*)(ws + off); off += (size_t)NS*NM*HD*2;        // 2097152
  float2* U1f  = (float2*)(ws + off); off += (size_t)NS*HIDC*NM*2;      // 262144
  float2* S1f  = (float2*)(ws + off); off += (size_t)NS*HIDC*NM*2;      // 262144
  float*  x1   =          (ws + off); off += (size_t)NS*HIDC*NPIX;      // 8388608
  float2* X1f  = (float2*)(ws + off); off += (size_t)NS*HIDC*NM*2;      // 262144

  fwd_dft_kernel<<<NS*IN_CH, 256, 0, stream>>>(v, Vf);
  gram_kernel<<<64, 256, 0, stream>>>(qwr, qwi, kwr, kwi, G2, Gdc);
  attn_kernel<<<512, 256, 0, stream>>>(Vf, G2, Gdc, A);
  uspec_kernel<<<256, 256, 0, stream>>>(Vf, vwr, vwi, A, Uf);
  mix1_kernel<<<256, 256, 0, stream>>>(Uf, u1wr, u1wi, s1w, U1f, S1f);
  x1dft_kernel<<<NS*HIDC, 256, 0, stream>>>(U1f, S1f, s1b, x1, X1f);
  final_kernel<<<64*8, 256, 0, stream>>>(X1f, u2wr, u2wi, x1, s2w, s2b, out);
}